// Round 4
// baseline (1528.379 us; speedup 1.0000x reference)
//
#include <hip/hip_runtime.h>
#include <hip/hip_bf16.h>

// RecurrentEntityNetwork on MI355X. S=128, B=1024, DOBJ=37, QD=11, D=256, M=20.
// Dual-dtype (runtime probe on prelu_a bits): inputs either bf16 or f32.
// phase1: mi = relu(MI@C^T+Cb) -> ws ; jv = relu(mi@V^T+Vb)@J2^T -> ws
// recur : 256 WGs x 512 thr (8 waves x 32-col resident weight slices),
//         4 batches/WG -> 80 mem rows = 5 clean 16-row tiles, 1 WG/CU.
//   R12: reg-resident weights (launch_bounds(512,2)), 1527us.
//   R13: 4 batches/WG, dup rows gone, 1350us. DS pipe still ~70% busy.
//   R14: DS-op diet.
//     (a) mem-gate folded into GEMM1: wave w (0..4) adds 1 MFMA/kt reusing
//         its already-loaded b_w fragment (gate phase reads 112->72 b128).
//     (b) permuted weight A-frags: tile ct = weight rows
//         colb+(lr>>2)*8+ct*4+(lr&3)  =>  lane owns 8 CONTIGUOUS out-cols
//         (colb+quad*8..+7). Restage/old/JWL/jv/mem-write become single
//         b128s (40 b64 -> 20 b128 per wave-step), conflict-free banks.
//   DEFERRED NORMALIZATION (mem raw + RS parity pads, scale applied lazily),
//   2 barriers/step. Epilogue fused per tile (rows unique, cols exclusive).

#define S_LEN 128
#define BSZ   1024
#define DOBJ  37
#define QD    11

typedef float f32x4 __attribute__((ext_vector_type(4)));
typedef short bf16x8 __attribute__((ext_vector_type(8)));
typedef short bf16x4 __attribute__((ext_vector_type(4)));

#define MFMA16(a, b, c) __builtin_amdgcn_mfma_f32_16x16x32_bf16((a), (b), (c), 0, 0, 0)

__device__ __forceinline__ float b2f(short h) {
    union { unsigned u; float f; } c; c.u = ((unsigned)(unsigned short)h) << 16; return c.f;
}
__device__ __forceinline__ short f2b(float x) {   // f32 -> bf16 RNE (init paths)
    union { float f; unsigned u; } c; c.f = x;
    return (short)((c.u + 0x7FFFu + ((c.u >> 16) & 1u)) >> 16);
}
__device__ __forceinline__ unsigned pkbf(float a, float b) {  // HW v_cvt_pk_bf16_f32
    union { __hip_bfloat162 h2; unsigned u; } c;
    c.h2 = __float22bfloat162_rn(make_float2(a, b));
    return c.u;
}
__device__ __forceinline__ float ld1(const void* p, int i, bool f32) {
    return f32 ? ((const float*)p)[i] : b2f(((const short*)p)[i]);
}
__device__ __forceinline__ bf16x8 ld8(const void* p, int i, bool f32) {  // i: 8-elem aligned
    if (!f32) return *(const bf16x8*)((const short*)p + i);
    const float* q = (const float*)p + i;
    bf16x8 r;
    #pragma unroll
    for (int e = 0; e < 8; ++e) r[e] = f2b(q[e]);
    return r;
}

// ---------------------------------------------------------------------------
// Phase 1: mi and jv for all (s,b). 64 rows/WG, grid 2048.  (unchanged)
// ---------------------------------------------------------------------------
__global__ __launch_bounds__(256, 2) void renet_phase1(
    const void* __restrict__ MI, const void* __restrict__ Cw, const void* __restrict__ Cb,
    const void* __restrict__ Vw, const void* __restrict__ Vb, const void* __restrict__ Jw,
    const void* __restrict__ PA, short* __restrict__ mi_out, short* __restrict__ jv_out)
{
    const bool F32 = (*(const unsigned*)PA == 0x3F800000u);
    __shared__ __align__(16) short A[64 * 264];
    __shared__ __align__(16) float MIL[64 * 40];
    __shared__ float VBL[256];

    const int t = threadIdx.x, r0 = blockIdx.x * 64;
    const int wv = t >> 6, lane = t & 63, lr = lane & 15, quad = lane >> 4;

    VBL[t] = ld1(Vb, t, F32);
    for (int c = 0; c < 10; ++c) {
        int idx = c * 256 + t;
        if (idx < 64 * 37) { int i = idx / 37, k = idx - i * 37; MIL[i * 40 + k] = ld1(MI, (r0 + i) * 37 + k, F32); }
    }
    __syncthreads();

    {   // mi = relu(MI @ Cw^T + Cb), column t; also store to ws
        float cw[DOBJ];
        #pragma unroll
        for (int k = 0; k < DOBJ; ++k) cw[k] = ld1(Cw, t * DOBJ + k, F32);
        float cb = ld1(Cb, t, F32);
        for (int i = 0; i < 64; ++i) {
            float a = cb;
            #pragma unroll
            for (int k = 0; k < DOBJ; ++k) a += MIL[i * 40 + k] * cw[k];
            short h = f2b(fmaxf(a, 0.f));
            A[i * 264 + t] = h;
            mi_out[(r0 + i) * 256 + t] = h;
        }
    }
    __syncthreads();

    const f32x4 Z4 = {0.f, 0.f, 0.f, 0.f};
    f32x4 acc[4][4];

    // v = mi @ Vw^T
    #pragma unroll
    for (int rt = 0; rt < 4; ++rt)
        #pragma unroll
        for (int nt = 0; nt < 4; ++nt) acc[rt][nt] = Z4;
    #pragma unroll
    for (int kt = 0; kt < 8; ++kt) {
        bf16x8 a[4];
        #pragma unroll
        for (int rt = 0; rt < 4; ++rt)
            a[rt] = *(const bf16x8*)&A[(rt * 16 + lr) * 264 + kt * 32 + quad * 8];
        #pragma unroll
        for (int nt = 0; nt < 4; ++nt) {
            int n = wv * 64 + nt * 16 + lr;
            bf16x8 b = ld8(Vw, n * 256 + kt * 32 + quad * 8, F32);
            #pragma unroll
            for (int rt = 0; rt < 4; ++rt) acc[rt][nt] = MFMA16(a[rt], b, acc[rt][nt]);
        }
    }
    __syncthreads();
    #pragma unroll
    for (int nt = 0; nt < 4; ++nt) {
        int n = wv * 64 + nt * 16 + lr;
        float vb = VBL[n];
        #pragma unroll
        for (int rt = 0; rt < 4; ++rt)
            #pragma unroll
            for (int r = 0; r < 4; ++r)
                A[(rt * 16 + quad * 4 + r) * 264 + n] = f2b(fmaxf(acc[rt][nt][r] + vb, 0.f));
    }
    __syncthreads();

    // jv = relu_v @ J2^T (J2 = Jw[:,256:512])
    #pragma unroll
    for (int rt = 0; rt < 4; ++rt)
        #pragma unroll
        for (int nt = 0; nt < 4; ++nt) acc[rt][nt] = Z4;
    #pragma unroll
    for (int kt = 0; kt < 8; ++kt) {
        bf16x8 a[4];
        #pragma unroll
        for (int rt = 0; rt < 4; ++rt)
            a[rt] = *(const bf16x8*)&A[(rt * 16 + lr) * 264 + kt * 32 + quad * 8];
        #pragma unroll
        for (int nt = 0; nt < 4; ++nt) {
            int n = wv * 64 + nt * 16 + lr;
            bf16x8 b = ld8(Jw, n * 768 + 256 + kt * 32 + quad * 8, F32);
            #pragma unroll
            for (int rt = 0; rt < 4; ++rt) acc[rt][nt] = MFMA16(a[rt], b, acc[rt][nt]);
        }
    }
    __syncthreads();
    #pragma unroll
    for (int nt = 0; nt < 4; ++nt) {
        int n = wv * 64 + nt * 16 + lr;
        #pragma unroll
        for (int rt = 0; rt < 4; ++rt)
            #pragma unroll
            for (int r = 0; r < 4; ++r)
                A[(rt * 16 + quad * 4 + r) * 264 + n] = f2b(acc[rt][nt][r]);
    }
    __syncthreads();
    for (int c = 0; c < 16; ++c) {
        int idx = c * 1024 + t * 4;
        int i = idx >> 8, k = idx & 255;
        *(ushort4*)&jv_out[(r0 + i) * 256 + k] = *(const ushort4*)&A[i * 264 + k];
    }
}

// ---------------------------------------------------------------------------
// Recurrence + head. grid 256 x 512 thr (8 waves x 32 cols), 4 batches/WG.
// LDS 107712 B; 1 WG/CU (VGPR 256-cap by design):
//   A1 [100*264] rows 0..79 mem RAW (batch=row/20, slot=row%20),
//       rows 80..99 keys. Pads per row (8 shorts):
//       mem rows : shorts 256-257 RS parity 0 (f32), 258-259 RS parity 1,
//                  260-261 gate logit (1 f32, pre-scaled), 262-263 spare
//       key rows : shorts 256-263 = 4 f32 gate key-logits [batch]
//   STG[80*264] relu(u*sc+Ub) restage + head scratch
//   SJ [ 4*264] sentence (mi) rows for the 4 batches
//   JWL[20*264] key-path J contribution + Jb, [slot][col] bf16
// Lane col ownership (permuted A-frags): cols colb + quad*8 + 0..7, where
//   value c (0..7) comes from acc[nt][c>>2][c&3].
// ---------------------------------------------------------------------------
__global__ __launch_bounds__(512, 2) void renet_recur(
    const short* __restrict__ mi, const short* __restrict__ jv,
    const void* __restrict__ Qin, const void* __restrict__ Qw, const void* __restrict__ Qb,
    const void* __restrict__ Uw, const void* __restrict__ Ub,
    const void* __restrict__ Jw, const void* __restrict__ Jb,
    const void* __restrict__ Ww, const void* __restrict__ Wb,
    const void* __restrict__ Hw, const void* __restrict__ Hb,
    const void* __restrict__ PA, const void* __restrict__ Emb, void* __restrict__ Out)
{
    const bool F32 = (*(const unsigned*)PA == 0x3F800000u);
    __shared__ __align__(16) short LDS[53856];    // 107712 B
    short* const A1  = LDS;            // 100*264 = 26400 shorts
    short* const STG = LDS + 26400;    //  80*264 = 21120
    short* const SJ  = LDS + 47520;    //   4*264 =  1056
    short* const JWL = LDS + 48576;    //  20*264 =  5280  (end 53856)

    const int t = threadIdx.x;                 // 0..511
    const int w8 = t >> 6;                     // wave 0..7
    const int lane = t & 63, lr = lane & 15, quad = lane >> 4;
    const int colb = w8 * 32;                  // this wave's 32-col slice
    const int lcol = colb + quad * 8;          // lane's 8 contiguous cols
    const float pa = ld1(PA, 0, F32);
    const f32x4 Z4 = {0.f, 0.f, 0.f, 0.f};
    const int bq0 = blockIdx.x * 4;

    float ub8[8];
    #pragma unroll
    for (int c = 0; c < 8; ++c) ub8[c] = ld1(Ub, lcol + c, F32);

    // resident weight fragments, PERMUTED: tile ct holds weight rows
    // colb + (lr>>2)*8 + ct*4 + (lr&3)  -> out-col(ct, quad*4+r) = lcol+ct*4+r
    const int prow = colb + (lr >> 2) * 8 + (lr & 3);
    bf16x8 uf[8][2], jf[8][2];
    #pragma unroll
    for (int kt = 0; kt < 8; ++kt)
        #pragma unroll
        for (int ct = 0; ct < 2; ++ct) {
            uf[kt][ct] = ld8(Uw, (prow + ct * 4) * 256 + kt * 32 + quad * 8, F32);
            jf[kt][ct] = ld8(Jw, (prow + ct * 4) * 768 + kt * 32 + quad * 8, F32);
        }

    // keys -> A1 rows 80..99 (pads zeroed)
    for (int c = 0; c < 11; ++c) {
        int idx = c * 512 + t;
        if (idx < 20 * 264) {
            int row = idx / 264, k = idx - row * 264;
            A1[(80 + row) * 264 + k] = (k < 256) ? f2b(ld1(Emb, row * 256 + k, F32)) : (short)0;
        }
    }
    __syncthreads();

    // WKS = relu(Emb@Ww^T+Wb) (f32 in STG); 2 grps x 10 slots
    {
        const int col = t & 255, grp = t >> 8, m0p = grp * 10;
        float* WKS = (float*)STG;
        float wacc[10];
        #pragma unroll
        for (int mm = 0; mm < 10; ++mm) wacc[mm] = 0.f;
        for (int c = 0; c < 32; ++c) {
            bf16x8 wv8 = ld8(Ww, col * 256 + c * 8, F32);
            float wf[8];
            #pragma unroll
            for (int e = 0; e < 8; ++e) wf[e] = b2f(wv8[e]);
            #pragma unroll
            for (int mm = 0; mm < 10; ++mm) {
                bf16x8 e8 = *(const bf16x8*)&A1[(80 + m0p + mm) * 264 + c * 8];
                float s = 0.f;
                #pragma unroll
                for (int e = 0; e < 8; ++e) s += b2f(e8[e]) * wf[e];
                wacc[mm] += s;
            }
        }
        float wb = ld1(Wb, col, F32);
        #pragma unroll
        for (int mm = 0; mm < 10; ++mm) WKS[(m0p + mm) * 256 + col] = fmaxf(wacc[mm] + wb, 0.f);
    }
    // mem rows 0..79 = keys raw (slot = row%20); RS par0 := 1.0 (step 0 uses
    // raw keys, reference normalizes only AFTER the first update); RS par1 := 0
    for (int c = 0; c < 42; ++c) {
        int idx = c * 512 + t;
        if (idx < 80 * 264) {
            int row = idx / 264, k = idx - row * 264;
            short v = (k < 256) ? A1[(80 + row % 20) * 264 + k] : (short)0;
            if (k == 256 || k == 257) v = (k == 257) ? (short)0x3F80 : (short)0;  // 1.0f LE halves
            A1[idx] = v;
        }
    }
    __syncthreads();

    // JWL[slot][col] = (WKS @ J3^T)[slot][col] + Jb[col]
    {
        const int col = t & 255, grp = t >> 8, m0p = grp * 10;
        const float* WKS = (const float*)STG;
        const float jb = ld1(Jb, col, F32);
        float jacc[10];
        #pragma unroll
        for (int mm = 0; mm < 10; ++mm) jacc[mm] = 0.f;
        for (int c = 0; c < 32; ++c) {
            bf16x8 j8 = ld8(Jw, col * 768 + 512 + c * 8, F32);
            float jfv[8];
            #pragma unroll
            for (int e = 0; e < 8; ++e) jfv[e] = b2f(j8[e]);
            #pragma unroll
            for (int mm = 0; mm < 10; ++mm) {
                float4 w0 = *(const float4*)&WKS[(m0p + mm) * 256 + c * 8];
                float4 w1 = *(const float4*)&WKS[(m0p + mm) * 256 + c * 8 + 4];
                jacc[mm] += w0.x * jfv[0] + w0.y * jfv[1] + w0.z * jfv[2] + w0.w * jfv[3]
                          + w1.x * jfv[4] + w1.y * jfv[5] + w1.z * jfv[6] + w1.w * jfv[7];
            }
        }
        #pragma unroll
        for (int mm = 0; mm < 10; ++mm) JWL[(m0p + mm) * 264 + col] = f2b(jacc[mm] + jb);
    }

    // stage sentences s=0 (4 batches)
    ushort4 pf_mi = {0, 0, 0, 0};
    if (t < 256) {
        pf_mi = *(const ushort4*)&mi[(bq0 + (t >> 6)) * 256 + (t & 63) * 4];
        *(ushort4*)&SJ[(t >> 6) * 264 + (t & 63) * 4] = pf_mi;
    }
    __syncthreads();

    for (int s = 0; s < S_LEN; ++s) {
        const int parO = (s & 1) << 1, parN = 2 - parO;   // short-offsets 0 / 2

        // prefetch next sentences
        if (s + 1 < S_LEN && t < 256)
            pf_mi = *(const ushort4*)&mi[((s + 1) * BSZ + bq0 + (t >> 6)) * 256 + (t & 63) * 4];

        // jv early (L2-hot), 4 batches x lane's 8 cols
        const bf16x8 jva = *(const bf16x8*)&jv[(s * BSZ + bq0 + 0) * 256 + lcol];
        const bf16x8 jvb = *(const bf16x8*)&jv[(s * BSZ + bq0 + 1) * 256 + lcol];
        const bf16x8 jvc = *(const bf16x8*)&jv[(s * BSZ + bq0 + 2) * 256 + lcol];
        const bf16x8 jvd = *(const bf16x8*)&jv[(s * BSZ + bq0 + 3) * 256 + lcol];

        // sc_old per tile (row = nt*16+lr)
        float sc_o[5];
        #pragma unroll
        for (int nt = 0; nt < 5; ++nt)
            sc_o[nt] = 1.f / (sqrtf(*(const float*)&A1[(nt * 16 + lr) * 264 + 256 + parO]) + 1e-12f);

        // ---- key-gate: sent x keys^T, waves 5/6 (tiles rows 80-95 / 84-99;
        //      dup rows 84-95 write identical bits)
        if (w8 == 5 || w8 == 6) {
            const int base = (w8 == 5) ? 80 : 84;
            f32x4 ag = Z4;
            #pragma unroll
            for (int kt = 0; kt < 8; ++kt) {
                bf16x8 a = *(const bf16x8*)&SJ[lr * 264 + kt * 32 + quad * 8];   // rows>=4 garbage, discarded
                bf16x8 b = *(const bf16x8*)&A1[(base + lr) * 264 + kt * 32 + quad * 8];
                ag = MFMA16(a, b, ag);
            }
            if (quad == 0) *(f32x4*)&A1[(base + lr) * 264 + 256] = ag;   // 4 f32 logits
        }

        // ---- GEMM1 (transposed): u^T = U_slice(A) x mem_raw^T(B)
        //      + mem-gate folded: wave w (0..4) reuses its b_w fragment
        f32x4 accg = Z4;
        f32x4 acc[5][2];
        #pragma unroll
        for (int nt = 0; nt < 5; ++nt) { acc[nt][0] = Z4; acc[nt][1] = Z4; }
        #pragma unroll
        for (int kt = 0; kt < 8; ++kt) {
            bf16x8 b0 = *(const bf16x8*)&A1[( 0 + lr) * 264 + kt * 32 + quad * 8];
            bf16x8 b1 = *(const bf16x8*)&A1[(16 + lr) * 264 + kt * 32 + quad * 8];
            bf16x8 b2 = *(const bf16x8*)&A1[(32 + lr) * 264 + kt * 32 + quad * 8];
            bf16x8 b3 = *(const bf16x8*)&A1[(48 + lr) * 264 + kt * 32 + quad * 8];
            bf16x8 b4 = *(const bf16x8*)&A1[(64 + lr) * 264 + kt * 32 + quad * 8];
            if (w8 < 5) {     // wave-uniform branch; reuse already-loaded b_w
                bf16x8 sjf = *(const bf16x8*)&SJ[lr * 264 + kt * 32 + quad * 8];
                if      (w8 == 0) accg = MFMA16(sjf, b0, accg);
                else if (w8 == 1) accg = MFMA16(sjf, b1, accg);
                else if (w8 == 2) accg = MFMA16(sjf, b2, accg);
                else if (w8 == 3) accg = MFMA16(sjf, b3, accg);
                else              accg = MFMA16(sjf, b4, accg);
            }
            acc[0][0] = MFMA16(uf[kt][0], b0, acc[0][0]);
            acc[1][0] = MFMA16(uf[kt][0], b1, acc[1][0]);
            acc[2][0] = MFMA16(uf[kt][0], b2, acc[2][0]);
            acc[3][0] = MFMA16(uf[kt][0], b3, acc[3][0]);
            acc[4][0] = MFMA16(uf[kt][0], b4, acc[4][0]);
            acc[0][1] = MFMA16(uf[kt][1], b0, acc[0][1]);
            acc[1][1] = MFMA16(uf[kt][1], b1, acc[1][1]);
            acc[2][1] = MFMA16(uf[kt][1], b2, acc[2][1]);
            acc[3][1] = MFMA16(uf[kt][1], b3, acc[3][1]);
            acc[4][1] = MFMA16(uf[kt][1], b4, acc[4][1]);
        }
        // mem-gate logit write (pre-scaled), wave w owns tile w
        if (w8 < 5 && quad == 0) {
            const int row = w8 * 16 + lr;
            const int bi = row / 20;
            float g = (bi == 0) ? accg[0] : (bi == 1) ? accg[1] : (bi == 2) ? accg[2] : accg[3];
            float scw = (w8 == 0) ? sc_o[0] : (w8 == 1) ? sc_o[1] : (w8 == 2) ? sc_o[2]
                      : (w8 == 3) ? sc_o[3] : sc_o[4];
            *(float*)&A1[row * 264 + 260] = g * scw;
        }
        // restage relu(u*sc + Ub) -> STG, one b128 per (nt): lane's 8 cols
        #pragma unroll
        for (int nt = 0; nt < 5; ++nt) {
            float v[8];
            #pragma unroll
            for (int c = 0; c < 8; ++c)
                v[c] = fmaxf(acc[nt][c >> 2][c & 3] * sc_o[nt] + ub8[c], 0.f);
            uint4 pk;
            pk.x = pkbf(v[0], v[1]); pk.y = pkbf(v[2], v[3]);
            pk.z = pkbf(v[4], v[5]); pk.w = pkbf(v[6], v[7]);
            *(uint4*)&STG[(nt * 16 + lr) * 264 + lcol] = pk;
        }
        if (t < 80) *(float*)&A1[t * 264 + 256 + parN] = 0.f;   // zero RS_new
        __syncthreads();                                        // B_a

        // ---- GEMM2 (transposed): jU^T = J1_slice(A) x relu_u^T(B), reuse acc
        #pragma unroll
        for (int nt = 0; nt < 5; ++nt) { acc[nt][0] = Z4; acc[nt][1] = Z4; }
        #pragma unroll
        for (int kt = 0; kt < 8; ++kt) {
            bf16x8 b0 = *(const bf16x8*)&STG[( 0 + lr) * 264 + kt * 32 + quad * 8];
            bf16x8 b1 = *(const bf16x8*)&STG[(16 + lr) * 264 + kt * 32 + quad * 8];
            bf16x8 b2 = *(const bf16x8*)&STG[(32 + lr) * 264 + kt * 32 + quad * 8];
            bf16x8 b3 = *(const bf16x8*)&STG[(48 + lr) * 264 + kt * 32 + quad * 8];
            bf16x8 b4 = *(const bf16x8*)&STG[(64 + lr) * 264 + kt * 32 + quad * 8];
            acc[0][0] = MFMA16(jf[kt][0], b0, acc[0][0]);
            acc[1][0] = MFMA16(jf[kt][0], b1, acc[1][0]);
            acc[2][0] = MFMA16(jf[kt][0], b2, acc[2][0]);
            acc[3][0] = MFMA16(jf[kt][0], b3, acc[3][0]);
            acc[4][0] = MFMA16(jf[kt][0], b4, acc[4][0]);
            acc[0][1] = MFMA16(jf[kt][1], b0, acc[0][1]);
            acc[1][1] = MFMA16(jf[kt][1], b1, acc[1][1]);
            acc[2][1] = MFMA16(jf[kt][1], b2, acc[2][1]);
            acc[3][1] = MFMA16(jf[kt][1], b3, acc[3][1]);
            acc[4][1] = MFMA16(jf[kt][1], b4, acc[4][1]);
        }

        // ---- epilogue, fused per tile (rows unique, cols wave-exclusive)
        #pragma unroll
        for (int nt = 0; nt < 5; ++nt) {
            const int row = nt * 16 + lr;
            const int bi = row / 20;
            const int slot = row - bi * 20;
            float gp = *(const float*)&A1[row * 264 + 260]
                     + ((const float*)&A1[(80 + slot) * 264 + 256])[bi];
            float gate = 1.f / (1.f + __expf(-gp));
            bf16x8 jw8  = *(const bf16x8*)&JWL[slot * 264 + lcol];
            bf16x8 old8 = *(const bf16x8*)&A1[row * 264 + lcol];
            bf16x8 jv8  = (nt == 0) ? jva
                        : (nt == 1) ? ((lr < 4)  ? jva : jvb)
                        : (nt == 2) ? ((lr < 8)  ? jvb : jvc)
                        : (nt == 3) ? ((lr < 12) ? jvc : jvd)
                        :             jvd;
            float u8[8], ss = 0.f;
            #pragma unroll
            for (int c = 0; c < 8; ++c) {
                float j = acc[nt][c >> 2][c & 3] + b2f(jv8[c]) + b2f(jw8[c]);
                float cand = j > 0.f ? j : pa * j;
                float u = b2f(old8[c]) * sc_o[nt] + gate * cand;
                u8[c] = u;
                ss += u * u;
            }
            uint4 pk;
            pk.x = pkbf(u8[0], u8[1]); pk.y = pkbf(u8[2], u8[3]);
            pk.z = pkbf(u8[4], u8[5]); pk.w = pkbf(u8[6], u8[7]);
            *(uint4*)&A1[row * 264 + lcol] = pk;
            ss += __shfl_xor(ss, 16);
            ss += __shfl_xor(ss, 32);
            if (quad == 0)
                atomicAdd((float*)&A1[row * 264 + 256 + parN], ss);
        }
        // stage next sentences (SJ unread in phase B)
        if (t < 256) *(ushort4*)&SJ[(t >> 6) * 264 + (t & 63) * 4] = pf_mi;
        __syncthreads();                                        // B_c
    }

    // ---------------- attention + output head (mem raw; final RS at parity 0) --
    float* SF = (float*)STG;  // QF[0..1023] EN[1024..1103] AT[1104..1183] HC[1280..3327]
    #pragma unroll
    for (int it = 0; it < 2; ++it) {
        const int idx = it * 512 + t, col = idx & 255, bi = idx >> 8;
        float a = ld1(Qb, col, F32);
        #pragma unroll
        for (int k = 0; k < QD; ++k)
            a += ld1(Qin, (bq0 + bi) * QD + k, F32) * ld1(Qw, col * QD + k, F32);
        SF[bi * 256 + col] = fmaxf(a, 0.f);
    }
    __syncthreads();
    if (t < 80) {
        int bi = t / 20;
        float e = 0.f;
        for (int c = 0; c < 32; ++c) {
            bf16x8 mv = *(const bf16x8*)&A1[t * 264 + c * 8];
            #pragma unroll
            for (int e8 = 0; e8 < 8; ++e8) e += b2f(mv[e8]) * SF[bi * 256 + c * 8 + e8];
        }
        float scf = 1.f / (sqrtf(*(const float*)&A1[t * 264 + 256]) + 1e-12f);
        SF[1024 + t] = e * scf;
    }
    __syncthreads();
    if (t < 4) {
        float mx = -1e30f;
        for (int m = 0; m < 20; ++m) mx = fmaxf(mx, SF[1024 + t * 20 + m]);
        float sm = 0.f, ex[20];
        for (int m = 0; m < 20; ++m) { ex[m] = __expf(SF[1024 + t * 20 + m] - mx); sm += ex[m]; }
        float inv = 1.f / sm;
        for (int m = 0; m < 20; ++m) {
            float scf = 1.f / (sqrtf(*(const float*)&A1[(t * 20 + m) * 264 + 256]) + 1e-12f);
            SF[1104 + t * 20 + m] = ex[m] * inv * scf;   // fold row-norm into attn weight
        }
    }
    __syncthreads();
    #pragma unroll
    for (int it = 0; it < 2; ++it) {
        const int idx = it * 512 + t, col = idx & 255, bi = idx >> 8;
        float a = 0.f;
        for (int m = 0; m < 20; ++m)
            a += SF[1104 + bi * 20 + m] * b2f(A1[(bi * 20 + m) * 264 + col]);
        SF[1280 + bi * 512 + 256 + col] = a;
        SF[1280 + bi * 512 + col] = SF[bi * 256 + col];
    }
    __syncthreads();
    #pragma unroll
    for (int it = 0; it < 2; ++it) {
        const int idx = it * 512 + t, col = idx & 255, bi = idx >> 8;
        float o = ld1(Hb, col, F32);
        for (int c = 0; c < 64; ++c) {
            bf16x8 hv = ld8(Hw, col * 512 + c * 8, F32);
            #pragma unroll
            for (int e8 = 0; e8 < 8; ++e8) o += b2f(hv[e8]) * SF[1280 + bi * 512 + c * 8 + e8];
        }
        int oi = (bq0 + bi) * 256 + col;
        float v = fmaxf(o, 0.f);
        if (F32) ((float*)Out)[oi] = v; else ((short*)Out)[oi] = f2b(v);
    }
}

// ---------------------------------------------------------------------------
extern "C" void kernel_launch(void* const* d_in, const int* in_sizes, int n_in,
                              void* d_out, int out_size, void* d_ws, size_t ws_size,
                              hipStream_t stream) {
    (void)in_sizes; (void)n_in; (void)out_size; (void)ws_size;
    const void* MIp = d_in[0];
    const void* Qin = d_in[1];
    const void* Cw  = d_in[2];
    const void* Cb  = d_in[3];
    const void* Qw  = d_in[4];
    const void* Qb  = d_in[5];
    const void* Hw  = d_in[6];
    const void* Hb  = d_in[7];
    const void* Uw  = d_in[8];
    const void* Ub  = d_in[9];
    const void* Vw  = d_in[10];
    const void* Vb  = d_in[11];
    const void* Ww  = d_in[12];
    const void* Wb  = d_in[13];
    const void* Jw  = d_in[14];
    const void* Jb  = d_in[15];
    const void* PA  = d_in[16];
    const void* Emb = d_in[17];

    short* mi_ws = (short*)d_ws;                          // (S*B,256) bf16 = 64 MiB
    short* jv_ws = mi_ws + (size_t)S_LEN * BSZ * 256;     // (S*B,256) bf16 = 64 MiB

    renet_phase1<<<dim3(2048), dim3(256), 0, stream>>>(MIp, Cw, Cb, Vw, Vb, Jw, PA, mi_ws, jv_ws);
    renet_recur<<<dim3(256), dim3(512), 0, stream>>>(mi_ws, jv_ws, Qin, Qw, Qb, Uw, Ub,
                                                     Jw, Jb, Ww, Wb, Hw, Hb, PA, Emb, d_out);
}

// Round 5
// 1284.972 us; speedup vs baseline: 1.1894x; 1.1894x over previous
//
#include <hip/hip_runtime.h>
#include <hip/hip_bf16.h>

// RecurrentEntityNetwork on MI355X. S=128, B=1024, DOBJ=37, QD=11, D=256, M=20.
// Dual-dtype (runtime probe on prelu_a bits): inputs either bf16 or f32.
// phase1: mi = relu(MI@C^T+Cb) -> ws ; jv = relu(mi@V^T+Vb)@J2^T -> ws
// recur : 256 WGs x 512 thr (8 waves x 32-col resident weight slices),
//         4 batches/WG -> 80 mem rows = 5 clean 16-row tiles, 1 WG/CU.
//   R12: reg-resident weights (launch_bounds(512,2)), 1527us.
//   R13: 4 batches/WG, dup rows gone, 1350us.
//   R14: gate folded into GEMM1 + permuted b128 epilogue -- REGRESSED 1528:
//   conflicts -21% but branchy MFMA loop broke compiler scheduling
//   (MfmaUtil/VALUBusy both fell). DS pipe is NOT the binding constraint.
//   R15: revert gate fold + jv hoist (standalone gate phase, jv in phase B);
//   KEEP permuted weight A-frags: tile ct = weight rows
//   colb+(lr>>2)*8+ct*4+(lr&3) => lane owns 8 CONTIGUOUS out-cols
//   (colb+quad*8..+7); restage/old/JWL/jv/mem-write are single b128s.
//   DEFERRED NORMALIZATION (mem raw + RS parity pads, scale applied lazily),
//   2 barriers/step. Epilogue fused per tile (rows unique, cols exclusive).

#define S_LEN 128
#define BSZ   1024
#define DOBJ  37
#define QD    11

typedef float f32x4 __attribute__((ext_vector_type(4)));
typedef short bf16x8 __attribute__((ext_vector_type(8)));
typedef short bf16x4 __attribute__((ext_vector_type(4)));

#define MFMA16(a, b, c) __builtin_amdgcn_mfma_f32_16x16x32_bf16((a), (b), (c), 0, 0, 0)

__device__ __forceinline__ float b2f(short h) {
    union { unsigned u; float f; } c; c.u = ((unsigned)(unsigned short)h) << 16; return c.f;
}
__device__ __forceinline__ short f2b(float x) {   // f32 -> bf16 RNE (init paths)
    union { float f; unsigned u; } c; c.f = x;
    return (short)((c.u + 0x7FFFu + ((c.u >> 16) & 1u)) >> 16);
}
__device__ __forceinline__ unsigned pkbf(float a, float b) {  // HW v_cvt_pk_bf16_f32
    union { __hip_bfloat162 h2; unsigned u; } c;
    c.h2 = __float22bfloat162_rn(make_float2(a, b));
    return c.u;
}
__device__ __forceinline__ float ld1(const void* p, int i, bool f32) {
    return f32 ? ((const float*)p)[i] : b2f(((const short*)p)[i]);
}
__device__ __forceinline__ bf16x8 ld8(const void* p, int i, bool f32) {  // i: 8-elem aligned
    if (!f32) return *(const bf16x8*)((const short*)p + i);
    const float* q = (const float*)p + i;
    bf16x8 r;
    #pragma unroll
    for (int e = 0; e < 8; ++e) r[e] = f2b(q[e]);
    return r;
}

// ---------------------------------------------------------------------------
// Phase 1: mi and jv for all (s,b). 64 rows/WG, grid 2048.  (unchanged)
// ---------------------------------------------------------------------------
__global__ __launch_bounds__(256, 2) void renet_phase1(
    const void* __restrict__ MI, const void* __restrict__ Cw, const void* __restrict__ Cb,
    const void* __restrict__ Vw, const void* __restrict__ Vb, const void* __restrict__ Jw,
    const void* __restrict__ PA, short* __restrict__ mi_out, short* __restrict__ jv_out)
{
    const bool F32 = (*(const unsigned*)PA == 0x3F800000u);
    __shared__ __align__(16) short A[64 * 264];
    __shared__ __align__(16) float MIL[64 * 40];
    __shared__ float VBL[256];

    const int t = threadIdx.x, r0 = blockIdx.x * 64;
    const int wv = t >> 6, lane = t & 63, lr = lane & 15, quad = lane >> 4;

    VBL[t] = ld1(Vb, t, F32);
    for (int c = 0; c < 10; ++c) {
        int idx = c * 256 + t;
        if (idx < 64 * 37) { int i = idx / 37, k = idx - i * 37; MIL[i * 40 + k] = ld1(MI, (r0 + i) * 37 + k, F32); }
    }
    __syncthreads();

    {   // mi = relu(MI @ Cw^T + Cb), column t; also store to ws
        float cw[DOBJ];
        #pragma unroll
        for (int k = 0; k < DOBJ; ++k) cw[k] = ld1(Cw, t * DOBJ + k, F32);
        float cb = ld1(Cb, t, F32);
        for (int i = 0; i < 64; ++i) {
            float a = cb;
            #pragma unroll
            for (int k = 0; k < DOBJ; ++k) a += MIL[i * 40 + k] * cw[k];
            short h = f2b(fmaxf(a, 0.f));
            A[i * 264 + t] = h;
            mi_out[(r0 + i) * 256 + t] = h;
        }
    }
    __syncthreads();

    const f32x4 Z4 = {0.f, 0.f, 0.f, 0.f};
    f32x4 acc[4][4];

    // v = mi @ Vw^T
    #pragma unroll
    for (int rt = 0; rt < 4; ++rt)
        #pragma unroll
        for (int nt = 0; nt < 4; ++nt) acc[rt][nt] = Z4;
    #pragma unroll
    for (int kt = 0; kt < 8; ++kt) {
        bf16x8 a[4];
        #pragma unroll
        for (int rt = 0; rt < 4; ++rt)
            a[rt] = *(const bf16x8*)&A[(rt * 16 + lr) * 264 + kt * 32 + quad * 8];
        #pragma unroll
        for (int nt = 0; nt < 4; ++nt) {
            int n = wv * 64 + nt * 16 + lr;
            bf16x8 b = ld8(Vw, n * 256 + kt * 32 + quad * 8, F32);
            #pragma unroll
            for (int rt = 0; rt < 4; ++rt) acc[rt][nt] = MFMA16(a[rt], b, acc[rt][nt]);
        }
    }
    __syncthreads();
    #pragma unroll
    for (int nt = 0; nt < 4; ++nt) {
        int n = wv * 64 + nt * 16 + lr;
        float vb = VBL[n];
        #pragma unroll
        for (int rt = 0; rt < 4; ++rt)
            #pragma unroll
            for (int r = 0; r < 4; ++r)
                A[(rt * 16 + quad * 4 + r) * 264 + n] = f2b(fmaxf(acc[rt][nt][r] + vb, 0.f));
    }
    __syncthreads();

    // jv = relu_v @ J2^T (J2 = Jw[:,256:512])
    #pragma unroll
    for (int rt = 0; rt < 4; ++rt)
        #pragma unroll
        for (int nt = 0; nt < 4; ++nt) acc[rt][nt] = Z4;
    #pragma unroll
    for (int kt = 0; kt < 8; ++kt) {
        bf16x8 a[4];
        #pragma unroll
        for (int rt = 0; rt < 4; ++rt)
            a[rt] = *(const bf16x8*)&A[(rt * 16 + lr) * 264 + kt * 32 + quad * 8];
        #pragma unroll
        for (int nt = 0; nt < 4; ++nt) {
            int n = wv * 64 + nt * 16 + lr;
            bf16x8 b = ld8(Jw, n * 768 + 256 + kt * 32 + quad * 8, F32);
            #pragma unroll
            for (int rt = 0; rt < 4; ++rt) acc[rt][nt] = MFMA16(a[rt], b, acc[rt][nt]);
        }
    }
    __syncthreads();
    #pragma unroll
    for (int nt = 0; nt < 4; ++nt) {
        int n = wv * 64 + nt * 16 + lr;
        #pragma unroll
        for (int rt = 0; rt < 4; ++rt)
            #pragma unroll
            for (int r = 0; r < 4; ++r)
                A[(rt * 16 + quad * 4 + r) * 264 + n] = f2b(acc[rt][nt][r]);
    }
    __syncthreads();
    for (int c = 0; c < 16; ++c) {
        int idx = c * 1024 + t * 4;
        int i = idx >> 8, k = idx & 255;
        *(ushort4*)&jv_out[(r0 + i) * 256 + k] = *(const ushort4*)&A[i * 264 + k];
    }
}

// ---------------------------------------------------------------------------
// Recurrence + head. grid 256 x 512 thr (8 waves x 32 cols), 4 batches/WG.
// LDS 107712 B; 1 WG/CU (VGPR 256-cap by design):
//   A1 [100*264] rows 0..79 mem RAW (batch=row/20, slot=row%20),
//       rows 80..99 keys. Pads per row (8 shorts):
//       mem rows : shorts 256-257 RS parity 0 (f32), 258-259 RS parity 1,
//                  260-261 gate logit (1 f32, pre-scaled), 262-263 spare
//       key rows : shorts 256-263 = 4 f32 gate key-logits [batch]
//   STG[80*264] relu(u*sc+Ub) restage + head scratch
//   SJ [ 4*264] sentence (mi) rows for the 4 batches
//   JWL[20*264] key-path J contribution + Jb, [slot][col] bf16
// Lane col ownership (permuted A-frags): cols colb + quad*8 + 0..7, where
//   value c (0..7) comes from acc[nt][c>>2][c&3].
// ---------------------------------------------------------------------------
__global__ __launch_bounds__(512, 2) void renet_recur(
    const short* __restrict__ mi, const short* __restrict__ jv,
    const void* __restrict__ Qin, const void* __restrict__ Qw, const void* __restrict__ Qb,
    const void* __restrict__ Uw, const void* __restrict__ Ub,
    const void* __restrict__ Jw, const void* __restrict__ Jb,
    const void* __restrict__ Ww, const void* __restrict__ Wb,
    const void* __restrict__ Hw, const void* __restrict__ Hb,
    const void* __restrict__ PA, const void* __restrict__ Emb, void* __restrict__ Out)
{
    const bool F32 = (*(const unsigned*)PA == 0x3F800000u);
    __shared__ __align__(16) short LDS[53856];    // 107712 B
    short* const A1  = LDS;            // 100*264 = 26400 shorts
    short* const STG = LDS + 26400;    //  80*264 = 21120
    short* const SJ  = LDS + 47520;    //   4*264 =  1056
    short* const JWL = LDS + 48576;    //  20*264 =  5280  (end 53856)

    const int t = threadIdx.x;                 // 0..511
    const int w8 = t >> 6;                     // wave 0..7
    const int lane = t & 63, lr = lane & 15, quad = lane >> 4;
    const int colb = w8 * 32;                  // this wave's 32-col slice
    const int lcol = colb + quad * 8;          // lane's 8 contiguous cols
    const float pa = ld1(PA, 0, F32);
    const f32x4 Z4 = {0.f, 0.f, 0.f, 0.f};
    const int bq0 = blockIdx.x * 4;

    float ub8[8];
    #pragma unroll
    for (int c = 0; c < 8; ++c) ub8[c] = ld1(Ub, lcol + c, F32);

    // resident weight fragments, PERMUTED: tile ct holds weight rows
    // colb + (lr>>2)*8 + ct*4 + (lr&3)  -> out-col(ct, quad*4+r) = lcol+ct*4+r
    const int prow = colb + (lr >> 2) * 8 + (lr & 3);
    bf16x8 uf[8][2], jf[8][2];
    #pragma unroll
    for (int kt = 0; kt < 8; ++kt)
        #pragma unroll
        for (int ct = 0; ct < 2; ++ct) {
            uf[kt][ct] = ld8(Uw, (prow + ct * 4) * 256 + kt * 32 + quad * 8, F32);
            jf[kt][ct] = ld8(Jw, (prow + ct * 4) * 768 + kt * 32 + quad * 8, F32);
        }

    // keys -> A1 rows 80..99 (pads zeroed)
    for (int c = 0; c < 11; ++c) {
        int idx = c * 512 + t;
        if (idx < 20 * 264) {
            int row = idx / 264, k = idx - row * 264;
            A1[(80 + row) * 264 + k] = (k < 256) ? f2b(ld1(Emb, row * 256 + k, F32)) : (short)0;
        }
    }
    __syncthreads();

    // WKS = relu(Emb@Ww^T+Wb) (f32 in STG); 2 grps x 10 slots
    {
        const int col = t & 255, grp = t >> 8, m0p = grp * 10;
        float* WKS = (float*)STG;
        float wacc[10];
        #pragma unroll
        for (int mm = 0; mm < 10; ++mm) wacc[mm] = 0.f;
        for (int c = 0; c < 32; ++c) {
            bf16x8 wv8 = ld8(Ww, col * 256 + c * 8, F32);
            float wf[8];
            #pragma unroll
            for (int e = 0; e < 8; ++e) wf[e] = b2f(wv8[e]);
            #pragma unroll
            for (int mm = 0; mm < 10; ++mm) {
                bf16x8 e8 = *(const bf16x8*)&A1[(80 + m0p + mm) * 264 + c * 8];
                float s = 0.f;
                #pragma unroll
                for (int e = 0; e < 8; ++e) s += b2f(e8[e]) * wf[e];
                wacc[mm] += s;
            }
        }
        float wb = ld1(Wb, col, F32);
        #pragma unroll
        for (int mm = 0; mm < 10; ++mm) WKS[(m0p + mm) * 256 + col] = fmaxf(wacc[mm] + wb, 0.f);
    }
    // mem rows 0..79 = keys raw (slot = row%20); RS par0 := 1.0 (step 0 uses
    // raw keys, reference normalizes only AFTER the first update); RS par1 := 0
    for (int c = 0; c < 42; ++c) {
        int idx = c * 512 + t;
        if (idx < 80 * 264) {
            int row = idx / 264, k = idx - row * 264;
            short v = (k < 256) ? A1[(80 + row % 20) * 264 + k] : (short)0;
            if (k == 256 || k == 257) v = (k == 257) ? (short)0x3F80 : (short)0;  // 1.0f LE halves
            A1[idx] = v;
        }
    }
    __syncthreads();

    // JWL[slot][col] = (WKS @ J3^T)[slot][col] + Jb[col]
    {
        const int col = t & 255, grp = t >> 8, m0p = grp * 10;
        const float* WKS = (const float*)STG;
        const float jb = ld1(Jb, col, F32);
        float jacc[10];
        #pragma unroll
        for (int mm = 0; mm < 10; ++mm) jacc[mm] = 0.f;
        for (int c = 0; c < 32; ++c) {
            bf16x8 j8 = ld8(Jw, col * 768 + 512 + c * 8, F32);
            float jfv[8];
            #pragma unroll
            for (int e = 0; e < 8; ++e) jfv[e] = b2f(j8[e]);
            #pragma unroll
            for (int mm = 0; mm < 10; ++mm) {
                float4 w0 = *(const float4*)&WKS[(m0p + mm) * 256 + c * 8];
                float4 w1 = *(const float4*)&WKS[(m0p + mm) * 256 + c * 8 + 4];
                jacc[mm] += w0.x * jfv[0] + w0.y * jfv[1] + w0.z * jfv[2] + w0.w * jfv[3]
                          + w1.x * jfv[4] + w1.y * jfv[5] + w1.z * jfv[6] + w1.w * jfv[7];
            }
        }
        #pragma unroll
        for (int mm = 0; mm < 10; ++mm) JWL[(m0p + mm) * 264 + col] = f2b(jacc[mm] + jb);
    }

    // stage sentences s=0 (4 batches)
    ushort4 pf_mi = {0, 0, 0, 0};
    if (t < 256) {
        pf_mi = *(const ushort4*)&mi[(bq0 + (t >> 6)) * 256 + (t & 63) * 4];
        *(ushort4*)&SJ[(t >> 6) * 264 + (t & 63) * 4] = pf_mi;
    }
    __syncthreads();

    for (int s = 0; s < S_LEN; ++s) {
        const int parO = (s & 1) << 1, parN = 2 - parO;   // short-offsets 0 / 2

        // prefetch next sentences
        if (s + 1 < S_LEN && t < 256)
            pf_mi = *(const ushort4*)&mi[((s + 1) * BSZ + bq0 + (t >> 6)) * 256 + (t & 63) * 4];

        // sc_old per tile (row = nt*16+lr)
        float sc_o[5];
        #pragma unroll
        for (int nt = 0; nt < 5; ++nt)
            sc_o[nt] = 1.f / (sqrtf(*(const float*)&A1[(nt * 16 + lr) * 264 + 256 + parO]) + 1e-12f);

        // ---- gate: G^T = sent(A, rows 0..3 valid) x [mem;keys]^T(B), waves 0..6
        //      mem tiles 0..4 (rows 0-79), key tiles rows 80-95 / 84-99
        //      (dup rows 84-95 write identical bits: same dot product)
        if (w8 < 7) {
            const int base = (w8 < 5) ? w8 * 16 : (w8 == 5) ? 80 : 84;
            f32x4 ag = Z4;
            #pragma unroll
            for (int kt = 0; kt < 8; ++kt) {
                bf16x8 a = *(const bf16x8*)&SJ[lr * 264 + kt * 32 + quad * 8];   // rows>=4 garbage, discarded
                bf16x8 b = *(const bf16x8*)&A1[(base + lr) * 264 + kt * 32 + quad * 8];
                ag = MFMA16(a, b, ag);
            }
            if (quad == 0) {
                const int row = base + lr;
                if (row < 80) {
                    const int bi = row / 20;
                    float sg = 1.f / (sqrtf(*(const float*)&A1[row * 264 + 256 + parO]) + 1e-12f);
                    float gm = (bi == 0) ? ag[0] : (bi == 1) ? ag[1] : (bi == 2) ? ag[2] : ag[3];
                    *(float*)&A1[row * 264 + 260] = gm * sg;
                } else {
                    *(f32x4*)&A1[row * 264 + 256] = ag;   // 4 f32 logits
                }
            }
        }

        // ---- GEMM1 (transposed): u^T = U_slice(A, 2 col-tiles) x mem_raw^T(B)
        f32x4 acc[5][2];
        #pragma unroll
        for (int nt = 0; nt < 5; ++nt) { acc[nt][0] = Z4; acc[nt][1] = Z4; }
        #pragma unroll
        for (int kt = 0; kt < 8; ++kt) {
            bf16x8 b0 = *(const bf16x8*)&A1[( 0 + lr) * 264 + kt * 32 + quad * 8];
            bf16x8 b1 = *(const bf16x8*)&A1[(16 + lr) * 264 + kt * 32 + quad * 8];
            bf16x8 b2 = *(const bf16x8*)&A1[(32 + lr) * 264 + kt * 32 + quad * 8];
            bf16x8 b3 = *(const bf16x8*)&A1[(48 + lr) * 264 + kt * 32 + quad * 8];
            bf16x8 b4 = *(const bf16x8*)&A1[(64 + lr) * 264 + kt * 32 + quad * 8];
            acc[0][0] = MFMA16(uf[kt][0], b0, acc[0][0]);
            acc[1][0] = MFMA16(uf[kt][0], b1, acc[1][0]);
            acc[2][0] = MFMA16(uf[kt][0], b2, acc[2][0]);
            acc[3][0] = MFMA16(uf[kt][0], b3, acc[3][0]);
            acc[4][0] = MFMA16(uf[kt][0], b4, acc[4][0]);
            acc[0][1] = MFMA16(uf[kt][1], b0, acc[0][1]);
            acc[1][1] = MFMA16(uf[kt][1], b1, acc[1][1]);
            acc[2][1] = MFMA16(uf[kt][1], b2, acc[2][1]);
            acc[3][1] = MFMA16(uf[kt][1], b3, acc[3][1]);
            acc[4][1] = MFMA16(uf[kt][1], b4, acc[4][1]);
        }
        // restage relu(u*sc + Ub) -> STG, one b128 per (nt): lane's 8 cols
        #pragma unroll
        for (int nt = 0; nt < 5; ++nt) {
            float v[8];
            #pragma unroll
            for (int c = 0; c < 8; ++c)
                v[c] = fmaxf(acc[nt][c >> 2][c & 3] * sc_o[nt] + ub8[c], 0.f);
            uint4 pk;
            pk.x = pkbf(v[0], v[1]); pk.y = pkbf(v[2], v[3]);
            pk.z = pkbf(v[4], v[5]); pk.w = pkbf(v[6], v[7]);
            *(uint4*)&STG[(nt * 16 + lr) * 264 + lcol] = pk;
        }
        if (t < 80) *(float*)&A1[t * 264 + 256 + parN] = 0.f;   // zero RS_new
        __syncthreads();                                        // B_a

        // ---- jv direct from global (L2-hot), 4 batches x lane's 8 cols
        const bf16x8 jva = *(const bf16x8*)&jv[(s * BSZ + bq0 + 0) * 256 + lcol];
        const bf16x8 jvb = *(const bf16x8*)&jv[(s * BSZ + bq0 + 1) * 256 + lcol];
        const bf16x8 jvc = *(const bf16x8*)&jv[(s * BSZ + bq0 + 2) * 256 + lcol];
        const bf16x8 jvd = *(const bf16x8*)&jv[(s * BSZ + bq0 + 3) * 256 + lcol];

        // ---- GEMM2 (transposed): jU^T = J1_slice(A) x relu_u^T(B), reuse acc
        #pragma unroll
        for (int nt = 0; nt < 5; ++nt) { acc[nt][0] = Z4; acc[nt][1] = Z4; }
        #pragma unroll
        for (int kt = 0; kt < 8; ++kt) {
            bf16x8 b0 = *(const bf16x8*)&STG[( 0 + lr) * 264 + kt * 32 + quad * 8];
            bf16x8 b1 = *(const bf16x8*)&STG[(16 + lr) * 264 + kt * 32 + quad * 8];
            bf16x8 b2 = *(const bf16x8*)&STG[(32 + lr) * 264 + kt * 32 + quad * 8];
            bf16x8 b3 = *(const bf16x8*)&STG[(48 + lr) * 264 + kt * 32 + quad * 8];
            bf16x8 b4 = *(const bf16x8*)&STG[(64 + lr) * 264 + kt * 32 + quad * 8];
            acc[0][0] = MFMA16(jf[kt][0], b0, acc[0][0]);
            acc[1][0] = MFMA16(jf[kt][0], b1, acc[1][0]);
            acc[2][0] = MFMA16(jf[kt][0], b2, acc[2][0]);
            acc[3][0] = MFMA16(jf[kt][0], b3, acc[3][0]);
            acc[4][0] = MFMA16(jf[kt][0], b4, acc[4][0]);
            acc[0][1] = MFMA16(jf[kt][1], b0, acc[0][1]);
            acc[1][1] = MFMA16(jf[kt][1], b1, acc[1][1]);
            acc[2][1] = MFMA16(jf[kt][1], b2, acc[2][1]);
            acc[3][1] = MFMA16(jf[kt][1], b3, acc[3][1]);
            acc[4][1] = MFMA16(jf[kt][1], b4, acc[4][1]);
        }

        // ---- epilogue, fused per tile (rows unique, cols wave-exclusive)
        #pragma unroll
        for (int nt = 0; nt < 5; ++nt) {
            const int row = nt * 16 + lr;
            const int bi = row / 20;
            const int slot = row - bi * 20;
            float gp = *(const float*)&A1[row * 264 + 260]
                     + ((const float*)&A1[(80 + slot) * 264 + 256])[bi];
            float gate = 1.f / (1.f + __expf(-gp));
            bf16x8 jw8  = *(const bf16x8*)&JWL[slot * 264 + lcol];
            bf16x8 old8 = *(const bf16x8*)&A1[row * 264 + lcol];
            bf16x8 jv8  = (nt == 0) ? jva
                        : (nt == 1) ? ((lr < 4)  ? jva : jvb)
                        : (nt == 2) ? ((lr < 8)  ? jvb : jvc)
                        : (nt == 3) ? ((lr < 12) ? jvc : jvd)
                        :             jvd;
            float u8[8], ss = 0.f;
            #pragma unroll
            for (int c = 0; c < 8; ++c) {
                float j = acc[nt][c >> 2][c & 3] + b2f(jv8[c]) + b2f(jw8[c]);
                float cand = j > 0.f ? j : pa * j;
                float u = b2f(old8[c]) * sc_o[nt] + gate * cand;
                u8[c] = u;
                ss += u * u;
            }
            uint4 pk;
            pk.x = pkbf(u8[0], u8[1]); pk.y = pkbf(u8[2], u8[3]);
            pk.z = pkbf(u8[4], u8[5]); pk.w = pkbf(u8[6], u8[7]);
            *(uint4*)&A1[row * 264 + lcol] = pk;
            ss += __shfl_xor(ss, 16);
            ss += __shfl_xor(ss, 32);
            if (quad == 0)
                atomicAdd((float*)&A1[row * 264 + 256 + parN], ss);
        }
        // stage next sentences (SJ unread in phase B)
        if (t < 256) *(ushort4*)&SJ[(t >> 6) * 264 + (t & 63) * 4] = pf_mi;
        __syncthreads();                                        // B_c
    }

    // ---------------- attention + output head (mem raw; final RS at parity 0) --
    float* SF = (float*)STG;  // QF[0..1023] EN[1024..1103] AT[1104..1183] HC[1280..3327]
    #pragma unroll
    for (int it = 0; it < 2; ++it) {
        const int idx = it * 512 + t, col = idx & 255, bi = idx >> 8;
        float a = ld1(Qb, col, F32);
        #pragma unroll
        for (int k = 0; k < QD; ++k)
            a += ld1(Qin, (bq0 + bi) * QD + k, F32) * ld1(Qw, col * QD + k, F32);
        SF[bi * 256 + col] = fmaxf(a, 0.f);
    }
    __syncthreads();
    if (t < 80) {
        int bi = t / 20;
        float e = 0.f;
        for (int c = 0; c < 32; ++c) {
            bf16x8 mv = *(const bf16x8*)&A1[t * 264 + c * 8];
            #pragma unroll
            for (int e8 = 0; e8 < 8; ++e8) e += b2f(mv[e8]) * SF[bi * 256 + c * 8 + e8];
        }
        float scf = 1.f / (sqrtf(*(const float*)&A1[t * 264 + 256]) + 1e-12f);
        SF[1024 + t] = e * scf;
    }
    __syncthreads();
    if (t < 4) {
        float mx = -1e30f;
        for (int m = 0; m < 20; ++m) mx = fmaxf(mx, SF[1024 + t * 20 + m]);
        float sm = 0.f, ex[20];
        for (int m = 0; m < 20; ++m) { ex[m] = __expf(SF[1024 + t * 20 + m] - mx); sm += ex[m]; }
        float inv = 1.f / sm;
        for (int m = 0; m < 20; ++m) {
            float scf = 1.f / (sqrtf(*(const float*)&A1[(t * 20 + m) * 264 + 256]) + 1e-12f);
            SF[1104 + t * 20 + m] = ex[m] * inv * scf;   // fold row-norm into attn weight
        }
    }
    __syncthreads();
    #pragma unroll
    for (int it = 0; it < 2; ++it) {
        const int idx = it * 512 + t, col = idx & 255, bi = idx >> 8;
        float a = 0.f;
        for (int m = 0; m < 20; ++m)
            a += SF[1104 + bi * 20 + m] * b2f(A1[(bi * 20 + m) * 264 + col]);
        SF[1280 + bi * 512 + 256 + col] = a;
        SF[1280 + bi * 512 + col] = SF[bi * 256 + col];
    }
    __syncthreads();
    #pragma unroll
    for (int it = 0; it < 2; ++it) {
        const int idx = it * 512 + t, col = idx & 255, bi = idx >> 8;
        float o = ld1(Hb, col, F32);
        for (int c = 0; c < 64; ++c) {
            bf16x8 hv = ld8(Hw, col * 512 + c * 8, F32);
            #pragma unroll
            for (int e8 = 0; e8 < 8; ++e8) o += b2f(hv[e8]) * SF[1280 + bi * 512 + c * 8 + e8];
        }
        int oi = (bq0 + bi) * 256 + col;
        float v = fmaxf(o, 0.f);
        if (F32) ((float*)Out)[oi] = v; else ((short*)Out)[oi] = f2b(v);
    }
}

// ---------------------------------------------------------------------------
extern "C" void kernel_launch(void* const* d_in, const int* in_sizes, int n_in,
                              void* d_out, int out_size, void* d_ws, size_t ws_size,
                              hipStream_t stream) {
    (void)in_sizes; (void)n_in; (void)out_size; (void)ws_size;
    const void* MIp = d_in[0];
    const void* Qin = d_in[1];
    const void* Cw  = d_in[2];
    const void* Cb  = d_in[3];
    const void* Qw  = d_in[4];
    const void* Qb  = d_in[5];
    const void* Hw  = d_in[6];
    const void* Hb  = d_in[7];
    const void* Uw  = d_in[8];
    const void* Ub  = d_in[9];
    const void* Vw  = d_in[10];
    const void* Vb  = d_in[11];
    const void* Ww  = d_in[12];
    const void* Wb  = d_in[13];
    const void* Jw  = d_in[14];
    const void* Jb  = d_in[15];
    const void* PA  = d_in[16];
    const void* Emb = d_in[17];

    short* mi_ws = (short*)d_ws;                          // (S*B,256) bf16 = 64 MiB
    short* jv_ws = mi_ws + (size_t)S_LEN * BSZ * 256;     // (S*B,256) bf16 = 64 MiB

    renet_phase1<<<dim3(2048), dim3(256), 0, stream>>>(MIp, Cw, Cb, Vw, Vb, Jw, PA, mi_ws, jv_ws);
    renet_recur<<<dim3(256), dim3(512), 0, stream>>>(mi_ws, jv_ws, Qin, Qw, Qb, Uw, Ub,
                                                     Jw, Jb, Ww, Wb, Hw, Hb, PA, Emb, d_out);
}